// Round 1
// baseline (173.833 us; speedup 1.0000x reference)
//
#include <hip/hip_runtime.h>

// N=1000 atoms, S=13 shifts, ncut=2 at current problem size (kernels are
// written generically off in_sizes, assuming ncut<=4 and n%... handled).
//
// Output layout (float32): [ d2[P] | mask0[P] | mask1[P] ... ]
//   P  = n*(n-1)/2 + S*n*n
//   d2[0:Pc)           = in-cell triu pairs, row-major (i<j)
//   d2[Pc + s*n*n + i*n + j] = shifted-image pair (s,i,j)
// Masks written as float 0.0/1.0 (JAX promotes the (f32,i32) tuple to f32).
//
// All distance math in f64 to match the numpy-f64 validator reference at the
// mask boundary (d2 < cutoff^2); d2 itself stored as f32 (threshold is 2%).

__global__ void __launch_bounds__(256) tri_kernel(
    const float* __restrict__ pos,
    const float* __restrict__ cutoffs,
    int ncut, int n,
    float* __restrict__ out, long long P)
{
    int j = blockIdx.x * 256 + threadIdx.x;
    int i = blockIdx.y;
    if (j >= n || j <= i) return;

    double dx = (double)pos[3*i+0] - (double)pos[3*j+0];
    double dy = (double)pos[3*i+1] - (double)pos[3*j+1];
    double dz = (double)pos[3*i+2] - (double)pos[3*j+2];
    double d2 = dx*dx + dy*dy + dz*dz;

    // pairs before row i: i*(n-1) - i*(i-1)/2 ; position in row: j-i-1
    long long off = (long long)i * (n - 1) - ((long long)i * (i - 1)) / 2 + (j - i - 1);
    out[off] = (float)d2;
    for (int c = 0; c < ncut; ++c) {
        double cv = (double)cutoffs[c];
        out[(long long)(c + 1) * P + off] = (d2 < cv * cv) ? 1.0f : 0.0f;
    }
}

__global__ void __launch_bounds__(256) shift_kernel(
    const float* __restrict__ pos,
    const float* __restrict__ cell,
    const float* __restrict__ shifts,
    const float* __restrict__ cutoffs,
    int ncut, int n,
    float* __restrict__ out, long long P, long long Pc)
{
    int i = blockIdx.y;
    int s = blockIdx.z;
    int jg = blockIdx.x * 256 + threadIdx.x;
    int j0 = jg << 2;
    if (j0 >= n) return;

    // shift_values[s] = shifts[s] @ cell, f64 (matches np order: sum over rows)
    double s0 = (double)shifts[3*s+0], s1 = (double)shifts[3*s+1], s2 = (double)shifts[3*s+2];
    double sv0 = s0 * (double)cell[0] + s1 * (double)cell[3] + s2 * (double)cell[6];
    double sv1 = s0 * (double)cell[1] + s1 * (double)cell[4] + s2 * (double)cell[7];
    double sv2 = s0 * (double)cell[2] + s1 * (double)cell[5] + s2 * (double)cell[8];

    double pix = (double)pos[3*i+0];
    double piy = (double)pos[3*i+1];
    double piz = (double)pos[3*i+2];

    double cut2[4];
    for (int c = 0; c < ncut; ++c) { double cv = (double)cutoffs[c]; cut2[c] = cv * cv; }

    long long t0 = ((long long)s * n + i) * (long long)n + j0;

    if (j0 + 4 <= n) {
        // 4 consecutive atoms j0..j0+3 = 12 floats; 16B-aligned since j0%4==0
        const float4* pj = (const float4*)(pos + 3 * j0);
        float4 a = pj[0], b = pj[1], c4 = pj[2];
        float jx[4] = {a.x, a.w, b.z, c4.y};
        float jy[4] = {a.y, b.x, b.w, c4.z};
        float jz[4] = {a.z, b.y, c4.x, c4.w};

        float d2f[4];
        float mf[4][4];
        for (int k = 0; k < 4; ++k) {
            double dx = (pix - (double)jx[k]) + sv0;
            double dy = (piy - (double)jy[k]) + sv1;
            double dz = (piz - (double)jz[k]) + sv2;
            double d2 = dx*dx + dy*dy + dz*dz;
            d2f[k] = (float)d2;
            for (int c = 0; c < ncut; ++c) mf[c][k] = (d2 < cut2[c]) ? 1.0f : 0.0f;
        }
        // Pc, P, t0 all divisible by 4 -> float4 stores are 16B-aligned
        *(float4*)(out + Pc + t0) = make_float4(d2f[0], d2f[1], d2f[2], d2f[3]);
        for (int c = 0; c < ncut; ++c)
            *(float4*)(out + (long long)(c + 1) * P + Pc + t0) =
                make_float4(mf[c][0], mf[c][1], mf[c][2], mf[c][3]);
    } else {
        // generic tail (unused at n=1000)
        for (int j = j0; j < n; ++j) {
            double dx = (pix - (double)pos[3*j+0]) + sv0;
            double dy = (piy - (double)pos[3*j+1]) + sv1;
            double dz = (piz - (double)pos[3*j+2]) + sv2;
            double d2 = dx*dx + dy*dy + dz*dz;
            long long t = t0 + (j - j0);
            out[Pc + t] = (float)d2;
            for (int c = 0; c < ncut; ++c)
                out[(long long)(c + 1) * P + Pc + t] = (d2 < cut2[c]) ? 1.0f : 0.0f;
        }
    }
}

extern "C" void kernel_launch(void* const* d_in, const int* in_sizes, int n_in,
                              void* d_out, int out_size, void* d_ws, size_t ws_size,
                              hipStream_t stream)
{
    const float* pos     = (const float*)d_in[0];
    const float* cell    = (const float*)d_in[1];
    const float* shifts  = (const float*)d_in[2];
    const float* cutoffs = (const float*)d_in[3];
    int n    = in_sizes[0] / 3;   // 1000
    int S    = in_sizes[2] / 3;   // 13
    int ncut = in_sizes[3];       // 2

    long long Pc = (long long)n * (n - 1) / 2;          // 499500
    long long P  = Pc + (long long)S * n * n;           // 13499500
    float* out = (float*)d_out;

    dim3 gt((n + 255) / 256, n, 1);
    tri_kernel<<<gt, dim3(256), 0, stream>>>(pos, cutoffs, ncut, n, out, P);

    int ngx = (((n + 3) / 4) + 255) / 256;              // 1 at n=1000
    dim3 gs(ngx, n, S);
    shift_kernel<<<gs, dim3(256), 0, stream>>>(pos, cell, shifts, cutoffs, ncut, n, out, P, Pc);
}

// Round 2
// 170.897 us; speedup vs baseline: 1.0172x; 1.0172x over previous
//
#include <hip/hip_runtime.h>
#include <math.h>

// Single-kernel PBC neighbor-list distances + per-cutoff masks.
//
// Output layout (float32): [ d2[P] | mask0[P] | mask1[P] ... ]
//   P  = Pc + S*n*n,  Pc = n*(n-1)/2
//   p < Pc             : in-cell triu pair, row-major (i<j)
//   p = Pc + s*n*n+i*n+j : shifted-image pair (s,i,j)
// Masks written as float 0.0/1.0 (harness reads the whole buffer as f32).
//
// Each thread owns 4 consecutive output elements p0..p0+3 (p0 % 4 == 0).
// Requires n%4==0 (=> Pc%4==0, P%4==0, and every shifted 4-chunk stays in
// one (s,i) row with j0%4==0 -> aligned float4 loads/stores throughout).
// Scalar fallback kernel handles other n (unused at n=1000).
//
// Distance math in f64: matches the numpy-f64 validator at the mask
// boundary (d2 < cutoff^2); compute cost is ~4 us, kernel is store-bound.

__global__ void __launch_bounds__(256) nbr_kernel(
    const float* __restrict__ pos,
    const float* __restrict__ cell,
    const float* __restrict__ shifts,
    const float* __restrict__ cutoffs,
    int ncut, int n,
    float* __restrict__ out, long long P, long long Pc)
{
    long long p0 = ((long long)blockIdx.x * 256 + threadIdx.x) << 2;
    if (p0 >= P) return;

    double cut2[4];
    for (int c = 0; c < ncut; ++c) { double cv = (double)cutoffs[c]; cut2[c] = cv * cv; }

    float d2f[4];
    float mf[4][4];

    if (p0 >= Pc) {
        // ---- shifted-image region: all 4 elements share (s, i) ----
        long long q = p0 - Pc;
        unsigned nn = (unsigned)n * (unsigned)n;
        unsigned s  = (unsigned)((unsigned long long)q / nn);
        unsigned r  = (unsigned)((unsigned long long)q - (unsigned long long)s * nn);
        unsigned i  = r / (unsigned)n;
        unsigned j0 = r - i * (unsigned)n;

        double s0 = (double)shifts[3*s+0], s1 = (double)shifts[3*s+1], s2 = (double)shifts[3*s+2];
        double sv0 = s0 * (double)cell[0] + s1 * (double)cell[3] + s2 * (double)cell[6];
        double sv1 = s0 * (double)cell[1] + s1 * (double)cell[4] + s2 * (double)cell[7];
        double sv2 = s0 * (double)cell[2] + s1 * (double)cell[5] + s2 * (double)cell[8];

        double pix = (double)pos[3*i+0];
        double piy = (double)pos[3*i+1];
        double piz = (double)pos[3*i+2];

        // 4 consecutive atoms j0..j0+3 = 12 floats, 48B-aligned (j0%4==0)
        const float4* pj = (const float4*)(pos + 3 * j0);
        float4 a = pj[0], b = pj[1], c4 = pj[2];
        float jx[4] = {a.x, a.w, b.z, c4.y};
        float jy[4] = {a.y, b.x, b.w, c4.z};
        float jz[4] = {a.z, b.y, c4.x, c4.w};

        for (int k = 0; k < 4; ++k) {
            double dx = (pix - (double)jx[k]) + sv0;
            double dy = (piy - (double)jy[k]) + sv1;
            double dz = (piz - (double)jz[k]) + sv2;
            double d2 = dx*dx + dy*dy + dz*dz;
            d2f[k] = (float)d2;
            for (int c = 0; c < ncut; ++c) mf[c][k] = (d2 < cut2[c]) ? 1.0f : 0.0f;
        }
    } else {
        // ---- in-cell triangular region: decode (i,j) per element ----
        // Row i starts at A(i) = i*(2n-1-i)/2, holds j in (i, n).
        long long tn = 2LL * n - 1;
        for (int k = 0; k < 4; ++k) {
            long long p = p0 + k;
            double D = (double)(tn * tn) - 8.0 * (double)p;
            long long i = (long long)(((double)tn - sqrt(D)) * 0.5);
            if (i < 0) i = 0;
            if (i > n - 2) i = n - 2;
            while ((i + 1) * (tn - (i + 1)) / 2 <= p) ++i;   // A(i+1) <= p
            while (i * (tn - i) / 2 > p) --i;                // A(i)   >  p
            long long j = p - i * (tn - i) / 2 + i + 1;

            double dx = (double)pos[3*i+0] - (double)pos[3*j+0];
            double dy = (double)pos[3*i+1] - (double)pos[3*j+1];
            double dz = (double)pos[3*i+2] - (double)pos[3*j+2];
            double d2 = dx*dx + dy*dy + dz*dz;
            d2f[k] = (float)d2;
            for (int c = 0; c < ncut; ++c) mf[c][k] = (d2 < cut2[c]) ? 1.0f : 0.0f;
        }
    }

    // Aligned float4 stores: p0%4==0 and P%4==0.
    *(float4*)(out + p0) = make_float4(d2f[0], d2f[1], d2f[2], d2f[3]);
    for (int c = 0; c < ncut; ++c)
        *(float4*)(out + (long long)(c + 1) * P + p0) =
            make_float4(mf[c][0], mf[c][1], mf[c][2], mf[c][3]);
}

// Scalar fallback for n % 4 != 0 (not used at n=1000).
__global__ void __launch_bounds__(256) nbr_kernel_scalar(
    const float* __restrict__ pos,
    const float* __restrict__ cell,
    const float* __restrict__ shifts,
    const float* __restrict__ cutoffs,
    int ncut, int n,
    float* __restrict__ out, long long P, long long Pc)
{
    long long p = (long long)blockIdx.x * 256 + threadIdx.x;
    if (p >= P) return;

    double cut2[4];
    for (int c = 0; c < ncut; ++c) { double cv = (double)cutoffs[c]; cut2[c] = cv * cv; }

    double d2;
    if (p >= Pc) {
        long long q = p - Pc;
        unsigned long long nn = (unsigned long long)n * n;
        unsigned s = (unsigned)(q / nn);
        unsigned long long r = q - (unsigned long long)s * nn;
        unsigned i = (unsigned)(r / n);
        unsigned j = (unsigned)(r - (unsigned long long)i * n);
        double s0 = (double)shifts[3*s+0], s1 = (double)shifts[3*s+1], s2 = (double)shifts[3*s+2];
        double sv0 = s0*(double)cell[0] + s1*(double)cell[3] + s2*(double)cell[6];
        double sv1 = s0*(double)cell[1] + s1*(double)cell[4] + s2*(double)cell[7];
        double sv2 = s0*(double)cell[2] + s1*(double)cell[5] + s2*(double)cell[8];
        double dx = ((double)pos[3*i+0] - (double)pos[3*j+0]) + sv0;
        double dy = ((double)pos[3*i+1] - (double)pos[3*j+1]) + sv1;
        double dz = ((double)pos[3*i+2] - (double)pos[3*j+2]) + sv2;
        d2 = dx*dx + dy*dy + dz*dz;
    } else {
        long long tn = 2LL * n - 1;
        double D = (double)(tn * tn) - 8.0 * (double)p;
        long long i = (long long)(((double)tn - sqrt(D)) * 0.5);
        if (i < 0) i = 0;
        if (i > n - 2) i = n - 2;
        while ((i + 1) * (tn - (i + 1)) / 2 <= p) ++i;
        while (i * (tn - i) / 2 > p) --i;
        long long j = p - i * (tn - i) / 2 + i + 1;
        double dx = (double)pos[3*i+0] - (double)pos[3*j+0];
        double dy = (double)pos[3*i+1] - (double)pos[3*j+1];
        double dz = (double)pos[3*i+2] - (double)pos[3*j+2];
        d2 = dx*dx + dy*dy + dz*dz;
    }
    out[p] = (float)d2;
    for (int c = 0; c < ncut; ++c)
        out[(long long)(c + 1) * P + p] = (d2 < cut2[c]) ? 1.0f : 0.0f;
}

extern "C" void kernel_launch(void* const* d_in, const int* in_sizes, int n_in,
                              void* d_out, int out_size, void* d_ws, size_t ws_size,
                              hipStream_t stream)
{
    const float* pos     = (const float*)d_in[0];
    const float* cell    = (const float*)d_in[1];
    const float* shifts  = (const float*)d_in[2];
    const float* cutoffs = (const float*)d_in[3];
    int n    = in_sizes[0] / 3;   // 1000
    int S    = in_sizes[2] / 3;   // 13
    int ncut = in_sizes[3];       // 2

    long long Pc = (long long)n * (n - 1) / 2;          // 499500
    long long P  = Pc + (long long)S * n * n;           // 13499500
    float* out = (float*)d_out;

    if ((n & 3) == 0) {
        long long chunks = P >> 2;                       // 3,374,875
        int blocks = (int)((chunks + 255) / 256);        // 13,184
        nbr_kernel<<<blocks, 256, 0, stream>>>(pos, cell, shifts, cutoffs,
                                               ncut, n, out, P, Pc);
    } else {
        int blocks = (int)((P + 255) / 256);
        nbr_kernel_scalar<<<blocks, 256, 0, stream>>>(pos, cell, shifts, cutoffs,
                                                      ncut, n, out, P, Pc);
    }
}